// Round 1
// baseline (1004.747 us; speedup 1.0000x reference)
//
#include <hip/hip_runtime.h>
#include <math.h>

#define N_NODES 100000
#define N_EDGES 1600000
#define DIM 32
#define N_GROUPS 64
#define BN_EPS 1e-5f

// ---- monotone float<->uint encoding for atomic max on floats ----
__device__ __forceinline__ unsigned enc_f32(float f) {
    unsigned u = __float_as_uint(f);
    return (u & 0x80000000u) ? ~u : (u | 0x80000000u);
}
__device__ __forceinline__ float dec_f32(unsigned u) {
    return (u & 0x80000000u) ? __uint_as_float(u & 0x7FFFFFFFu) : __uint_as_float(~u);
}

// Fold BN into weights: Wf[k][j] = W[k][j]*scale_j, shift_j = (b_j - mean_j)*scale_j + beta_j
// 5 blocks (lin0,lin1,lin2,conv0,conv1) x 1024 threads.
__global__ void fold_kernel(const float* __restrict__ lin_W, const float* __restrict__ lin_b,
                            const float* __restrict__ lin_gamma, const float* __restrict__ lin_beta,
                            const float* __restrict__ lin_mean, const float* __restrict__ lin_var,
                            const float* __restrict__ conv_W, const float* __restrict__ conv_b,
                            const float* __restrict__ conv_gamma, const float* __restrict__ conv_beta,
                            const float* __restrict__ conv_mean, const float* __restrict__ conv_var,
                            float* __restrict__ Wf,   // [5][32][32]
                            float* __restrict__ shf)  // [5][32]
{
    int l = blockIdx.x;      // 0..2 = lin, 3..4 = conv
    int t = threadIdx.x;     // 0..1023
    const float *W, *b, *gm, *bt, *mn, *vr;
    if (l < 3) {
        W = lin_W + l * DIM * DIM; b = lin_b + l * DIM; gm = lin_gamma + l * DIM;
        bt = lin_beta + l * DIM;   mn = lin_mean + l * DIM; vr = lin_var + l * DIM;
    } else {
        int c = l - 3;
        W = conv_W + c * DIM * DIM; b = conv_b + c * DIM; gm = conv_gamma + c * DIM;
        bt = conv_beta + c * DIM;   mn = conv_mean + c * DIM; vr = conv_var + c * DIM;
    }
    int j = t & (DIM - 1);
    float scale = gm[j] / sqrtf(vr[j] + BN_EPS);
    Wf[l * DIM * DIM + t] = W[t] * scale;
    if (t < DIM) shf[l * DIM + t] = (b[t] - mn[t]) * scale + bt[t];
}

// z = elu(h @ Wf + shift); Z accumulate; segment-max atomics.
// 256 threads = 8 rows/block; N divisible by 8 -> no tail.
template <bool FIRST>
__global__ __launch_bounds__(256) void lin_mlp_kernel(
        const float* __restrict__ h,       // [N,32]
        const float* __restrict__ Wf,      // [32,32] folded
        const float* __restrict__ shf,     // [32]
        const int* __restrict__ batch,     // [N]
        const float* __restrict__ lw_ptr,  // scalar layer weight
        float* __restrict__ Zout,          // [N,32]
        unsigned* __restrict__ segmax)     // [G,32] encoded
{
    __shared__ float Wl[DIM * DIM];
    __shared__ float sh[DIM];
    __shared__ float hl[8 * DIM];
    int t = threadIdx.x;
    for (int i = t; i < DIM * DIM; i += 256) Wl[i] = Wf[i];
    if (t < DIM) sh[t] = shf[t];
    int base = blockIdx.x * 8 * DIM;           // flat base of this block's 8 rows
    hl[t] = h[base + t];
    __syncthreads();

    int rl = t >> 5;        // local row 0..7
    int col = t & 31;
    int row = blockIdx.x * 8 + rl;

    float acc = sh[col];
#pragma unroll
    for (int k = 0; k < DIM; ++k) acc += hl[rl * DIM + k] * Wl[k * DIM + col];
    float z = acc > 0.f ? acc : expm1f(acc);
    float lw = lw_ptr[0];
    float zw = lw * z;
    float segval = FIRST ? z : zw;     // layer 0 pools unweighted z, layers 1-2 weighted
    if (FIRST) Zout[base + t] = zw;
    else       Zout[base + t] += zw;
    atomicMax(&segmax[batch[row] * DIM + col], enc_f32(segval));
}

// x' = elu((x + agg) @ Wf + shift)
__global__ __launch_bounds__(256) void conv_mlp_kernel(
        const float* __restrict__ x,
        const float* __restrict__ agg,
        const float* __restrict__ Wf,
        const float* __restrict__ shf,
        float* __restrict__ out)
{
    __shared__ float Wl[DIM * DIM];
    __shared__ float sh[DIM];
    __shared__ float hl[8 * DIM];
    int t = threadIdx.x;
    for (int i = t; i < DIM * DIM; i += 256) Wl[i] = Wf[i];
    if (t < DIM) sh[t] = shf[t];
    int base = blockIdx.x * 8 * DIM;
    hl[t] = x[base + t] + agg[base + t];
    __syncthreads();

    int rl = t >> 5;
    int col = t & 31;
    float acc = sh[col];
#pragma unroll
    for (int k = 0; k < DIM; ++k) acc += hl[rl * DIM + k] * Wl[k * DIM + col];
    out[base + rl * DIM + col] = acc > 0.f ? acc : expm1f(acc);
}

// agg[dst[e]] += x[src[e]] : 32 threads per edge, one column each.
__global__ __launch_bounds__(256) void segsum_kernel(
        const float* __restrict__ x,
        const int* __restrict__ src,
        const int* __restrict__ dst,
        float* __restrict__ agg)
{
    unsigned t = blockIdx.x * 256u + threadIdx.x;   // < E*32 = 51.2M, grid exact
    int e = t >> 5;
    int col = t & 31;
    int s = src[e];
    int d = dst[e];
    atomicAdd(&agg[d * DIM + col], x[s * DIM + col]);
}

// out[g][j] += decode(segmax[g][j])
__global__ void add_out_kernel(const unsigned* __restrict__ segmax, float* __restrict__ out) {
    int t = blockIdx.x * blockDim.x + threadIdx.x;  // 2048
    out[t] += dec_f32(segmax[t]);
}

extern "C" void kernel_launch(void* const* d_in, const int* in_sizes, int n_in,
                              void* d_out, int out_size, void* d_ws, size_t ws_size,
                              hipStream_t stream) {
    const float* x0        = (const float*)d_in[0];
    const int*   ei        = (const int*)d_in[1];     // (2,E): row0=src, row1=dst
    const int*   batch     = (const int*)d_in[2];
    const float* lw        = (const float*)d_in[3];
    const float* lin_W     = (const float*)d_in[4];
    const float* lin_b     = (const float*)d_in[5];
    const float* lin_gamma = (const float*)d_in[6];
    const float* lin_beta  = (const float*)d_in[7];
    const float* lin_mean  = (const float*)d_in[8];
    const float* lin_var   = (const float*)d_in[9];
    const float* conv_W    = (const float*)d_in[10];
    const float* conv_b    = (const float*)d_in[11];
    const float* conv_gamma= (const float*)d_in[12];
    const float* conv_beta = (const float*)d_in[13];
    const float* conv_mean = (const float*)d_in[14];
    const float* conv_var  = (const float*)d_in[15];

    float* out  = (float*)d_out;                 // [G*32]
    float* Z    = out + N_GROUPS * DIM;          // [N*32]
    float* xout = Z + (size_t)N_NODES * DIM;     // [N*32]

    char* p = (char*)d_ws;
    float*    agg   = (float*)p;    p += (size_t)N_NODES * DIM * sizeof(float);
    float*    xbuf  = (float*)p;    p += (size_t)N_NODES * DIM * sizeof(float);
    unsigned* segmx = (unsigned*)p; p += N_GROUPS * DIM * sizeof(unsigned);
    float*    Wf    = (float*)p;    p += 5 * DIM * DIM * sizeof(float);
    float*    shf   = (float*)p;    p += 5 * DIM * sizeof(float);

    const int* src = ei;
    const int* dst = ei + N_EDGES;

    const int mlp_blocks = N_NODES / 8;            // 12500
    const int seg_blocks = N_EDGES * 32 / 256;     // 200000

    hipMemsetAsync(out, 0, N_GROUPS * DIM * sizeof(float), stream);
    fold_kernel<<<5, 1024, 0, stream>>>(lin_W, lin_b, lin_gamma, lin_beta, lin_mean, lin_var,
                                        conv_W, conv_b, conv_gamma, conv_beta, conv_mean, conv_var,
                                        Wf, shf);

    // ---- layer 0 ----
    hipMemsetAsync(segmx, 0, N_GROUPS * DIM * sizeof(unsigned), stream);
    lin_mlp_kernel<true><<<mlp_blocks, 256, 0, stream>>>(x0, Wf, shf, batch, lw, Z, segmx);
    add_out_kernel<<<8, 256, 0, stream>>>(segmx, out);

    // ---- layer 1 ----
    hipMemsetAsync(agg, 0, (size_t)N_NODES * DIM * sizeof(float), stream);
    segsum_kernel<<<seg_blocks, 256, 0, stream>>>(x0, src, dst, agg);
    conv_mlp_kernel<<<mlp_blocks, 256, 0, stream>>>(x0, agg, Wf + 3 * DIM * DIM, shf + 3 * DIM, xbuf);
    hipMemsetAsync(segmx, 0, N_GROUPS * DIM * sizeof(unsigned), stream);
    lin_mlp_kernel<false><<<mlp_blocks, 256, 0, stream>>>(xbuf, Wf + 1 * DIM * DIM, shf + 1 * DIM,
                                                          batch, lw + 1, Z, segmx);
    add_out_kernel<<<8, 256, 0, stream>>>(segmx, out);

    // ---- layer 2 ----
    hipMemsetAsync(agg, 0, (size_t)N_NODES * DIM * sizeof(float), stream);
    segsum_kernel<<<seg_blocks, 256, 0, stream>>>(xbuf, src, dst, agg);
    conv_mlp_kernel<<<mlp_blocks, 256, 0, stream>>>(xbuf, agg, Wf + 4 * DIM * DIM, shf + 4 * DIM, xout);
    hipMemsetAsync(segmx, 0, N_GROUPS * DIM * sizeof(unsigned), stream);
    lin_mlp_kernel<false><<<mlp_blocks, 256, 0, stream>>>(xout, Wf + 2 * DIM * DIM, shf + 2 * DIM,
                                                          batch, lw + 2, Z, segmx);
    add_out_kernel<<<8, 256, 0, stream>>>(segmx, out);
}

// Round 2
// 582.101 us; speedup vs baseline: 1.7261x; 1.7261x over previous
//
#include <hip/hip_runtime.h>
#include <math.h>

#define N_NODES 100000
#define N_EDGES 1600000
#define DIM 32
#define N_GROUPS 64
#define BN_EPS 1e-5f

// ---- monotone float<->uint encoding for atomic max on floats ----
__device__ __forceinline__ unsigned enc_f32(float f) {
    unsigned u = __float_as_uint(f);
    return (u & 0x80000000u) ? ~u : (u | 0x80000000u);
}
__device__ __forceinline__ float dec_f32(unsigned u) {
    return (u & 0x80000000u) ? __uint_as_float(u & 0x7FFFFFFFu) : __uint_as_float(~u);
}

// Fold BN into weights: Wf[k][j] = W[k][j]*scale_j, shift_j = (b_j - mean_j)*scale_j + beta_j
__global__ void fold_kernel(const float* __restrict__ lin_W, const float* __restrict__ lin_b,
                            const float* __restrict__ lin_gamma, const float* __restrict__ lin_beta,
                            const float* __restrict__ lin_mean, const float* __restrict__ lin_var,
                            const float* __restrict__ conv_W, const float* __restrict__ conv_b,
                            const float* __restrict__ conv_gamma, const float* __restrict__ conv_beta,
                            const float* __restrict__ conv_mean, const float* __restrict__ conv_var,
                            float* __restrict__ Wf,   // [5][32][32]
                            float* __restrict__ shf)  // [5][32]
{
    int l = blockIdx.x;      // 0..2 = lin, 3..4 = conv
    int t = threadIdx.x;     // 0..1023
    const float *W, *b, *gm, *bt, *mn, *vr;
    if (l < 3) {
        W = lin_W + l * DIM * DIM; b = lin_b + l * DIM; gm = lin_gamma + l * DIM;
        bt = lin_beta + l * DIM;   mn = lin_mean + l * DIM; vr = lin_var + l * DIM;
    } else {
        int c = l - 3;
        W = conv_W + c * DIM * DIM; b = conv_b + c * DIM; gm = conv_gamma + c * DIM;
        bt = conv_beta + c * DIM;   mn = conv_mean + c * DIM; vr = conv_var + c * DIM;
    }
    int j = t & (DIM - 1);
    float scale = gm[j] / sqrtf(vr[j] + BN_EPS);
    Wf[l * DIM * DIM + t] = W[t] * scale;
    if (t < DIM) shf[l * DIM + t] = (b[t] - mn[t]) * scale + bt[t];
}

// z = elu(h @ Wf + shift); Z accumulate; hierarchical segment-max (batch is sorted:
// keep running max per thread, flush atomicMax only on group transition).
// Block = 256 threads, processes TILES_PER_BLOCK*8 = 128 rows.
#define TILES_PER_BLOCK 16
template <bool FIRST>
__global__ __launch_bounds__(256) void lin_mlp_kernel(
        const float* __restrict__ h,       // [N,32]
        const float* __restrict__ Wf,      // [32,32] folded
        const float* __restrict__ shf,     // [32]
        const int* __restrict__ batch,     // [N] sorted
        const float* __restrict__ lw_ptr,  // scalar layer weight
        float* __restrict__ Zout,          // [N,32]
        unsigned* __restrict__ segmax)     // [G,32] encoded
{
    __shared__ float Wl[DIM * DIM];
    __shared__ float sh[DIM];
    __shared__ float hl[8 * DIM];
    int t = threadIdx.x;
    for (int i = t; i < DIM * DIM; i += 256) Wl[i] = Wf[i];
    if (t < DIM) sh[t] = shf[t];
    __syncthreads();

    int rl = t >> 5;        // local row 0..7 within tile
    int col = t & 31;
    float lw = lw_ptr[0];
    int row0 = blockIdx.x * (TILES_PER_BLOCK * 8);

    float m = 0.f;
    int gcur = -1;

    for (int tile = 0; tile < TILES_PER_BLOCK; ++tile) {
        int rbase = row0 + tile * 8;
        if (rbase >= N_NODES) break;              // N % 8 == 0: tiles are all-or-nothing
        int base = rbase * DIM;
        __syncthreads();                          // WAR on hl
        hl[t] = h[base + t];
        __syncthreads();                          // RAW on hl

        float acc = sh[col];
#pragma unroll
        for (int k = 0; k < DIM; ++k) acc += hl[rl * DIM + k] * Wl[k * DIM + col];
        float z = acc > 0.f ? acc : expm1f(acc);
        float zw = lw * z;
        if (FIRST) Zout[base + t] = zw;
        else       Zout[base + t] += zw;

        float segval = FIRST ? z : zw;            // layer 0 pools unweighted z
        int g = batch[rbase + rl];
        if (g != gcur) {
            if (gcur >= 0) atomicMax(&segmax[gcur * DIM + col], enc_f32(m));
            gcur = g;
            m = segval;
        } else {
            m = fmaxf(m, segval);
        }
    }
    if (gcur >= 0) atomicMax(&segmax[gcur * DIM + col], enc_f32(m));
}

// x' = elu((x + agg) @ Wf + shift)
__global__ __launch_bounds__(256) void conv_mlp_kernel(
        const float* __restrict__ x,
        const float* __restrict__ agg,
        const float* __restrict__ Wf,
        const float* __restrict__ shf,
        float* __restrict__ out)
{
    __shared__ float Wl[DIM * DIM];
    __shared__ float sh[DIM];
    __shared__ float hl[8 * DIM];
    int t = threadIdx.x;
    for (int i = t; i < DIM * DIM; i += 256) Wl[i] = Wf[i];
    if (t < DIM) sh[t] = shf[t];
    int base = blockIdx.x * 8 * DIM;
    hl[t] = x[base + t] + agg[base + t];
    __syncthreads();

    int rl = t >> 5;
    int col = t & 31;
    float acc = sh[col];
#pragma unroll
    for (int k = 0; k < DIM; ++k) acc += hl[rl * DIM + k] * Wl[k * DIM + col];
    out[base + rl * DIM + col] = acc > 0.f ? acc : expm1f(acc);
}

// agg[dst[e]] += x[src[e]] : 32 threads per edge, one column each.
__global__ __launch_bounds__(256) void segsum_kernel(
        const float* __restrict__ x,
        const int* __restrict__ src,
        const int* __restrict__ dst,
        float* __restrict__ agg)
{
    unsigned t = blockIdx.x * 256u + threadIdx.x;   // < E*32 = 51.2M, grid exact
    int e = t >> 5;
    int col = t & 31;
    int s = src[e];
    int d = dst[e];
    atomicAdd(&agg[d * DIM + col], x[s * DIM + col]);
}

// out[g][j] += decode(segmax[g][j])
__global__ void add_out_kernel(const unsigned* __restrict__ segmax, float* __restrict__ out) {
    int t = blockIdx.x * blockDim.x + threadIdx.x;  // 2048
    out[t] += dec_f32(segmax[t]);
}

extern "C" void kernel_launch(void* const* d_in, const int* in_sizes, int n_in,
                              void* d_out, int out_size, void* d_ws, size_t ws_size,
                              hipStream_t stream) {
    const float* x0        = (const float*)d_in[0];
    const int*   ei        = (const int*)d_in[1];     // (2,E): row0=src, row1=dst
    const int*   batch     = (const int*)d_in[2];
    const float* lw        = (const float*)d_in[3];
    const float* lin_W     = (const float*)d_in[4];
    const float* lin_b     = (const float*)d_in[5];
    const float* lin_gamma = (const float*)d_in[6];
    const float* lin_beta  = (const float*)d_in[7];
    const float* lin_mean  = (const float*)d_in[8];
    const float* lin_var   = (const float*)d_in[9];
    const float* conv_W    = (const float*)d_in[10];
    const float* conv_b    = (const float*)d_in[11];
    const float* conv_gamma= (const float*)d_in[12];
    const float* conv_beta = (const float*)d_in[13];
    const float* conv_mean = (const float*)d_in[14];
    const float* conv_var  = (const float*)d_in[15];

    float* out  = (float*)d_out;                 // [G*32]
    float* Z    = out + N_GROUPS * DIM;          // [N*32]
    float* xout = Z + (size_t)N_NODES * DIM;     // [N*32]

    char* p = (char*)d_ws;
    float*    agg   = (float*)p;    p += (size_t)N_NODES * DIM * sizeof(float);
    float*    xbuf  = (float*)p;    p += (size_t)N_NODES * DIM * sizeof(float);
    unsigned* segmx = (unsigned*)p; p += N_GROUPS * DIM * sizeof(unsigned);
    float*    Wf    = (float*)p;    p += 5 * DIM * DIM * sizeof(float);
    float*    shf   = (float*)p;    p += 5 * DIM * sizeof(float);

    const int* src = ei;
    const int* dst = ei + N_EDGES;

    const int mlp_blocks  = N_NODES / 8;                                  // 12500
    const int linm_blocks = (N_NODES + TILES_PER_BLOCK * 8 - 1) / (TILES_PER_BLOCK * 8);  // 782
    const int seg_blocks  = N_EDGES * 32 / 256;                           // 200000

    hipMemsetAsync(out, 0, N_GROUPS * DIM * sizeof(float), stream);
    fold_kernel<<<5, 1024, 0, stream>>>(lin_W, lin_b, lin_gamma, lin_beta, lin_mean, lin_var,
                                        conv_W, conv_b, conv_gamma, conv_beta, conv_mean, conv_var,
                                        Wf, shf);

    // ---- layer 0 ----
    hipMemsetAsync(segmx, 0, N_GROUPS * DIM * sizeof(unsigned), stream);
    lin_mlp_kernel<true><<<linm_blocks, 256, 0, stream>>>(x0, Wf, shf, batch, lw, Z, segmx);
    add_out_kernel<<<8, 256, 0, stream>>>(segmx, out);

    // ---- layer 1 ----
    hipMemsetAsync(agg, 0, (size_t)N_NODES * DIM * sizeof(float), stream);
    segsum_kernel<<<seg_blocks, 256, 0, stream>>>(x0, src, dst, agg);
    conv_mlp_kernel<<<mlp_blocks, 256, 0, stream>>>(x0, agg, Wf + 3 * DIM * DIM, shf + 3 * DIM, xbuf);
    hipMemsetAsync(segmx, 0, N_GROUPS * DIM * sizeof(unsigned), stream);
    lin_mlp_kernel<false><<<linm_blocks, 256, 0, stream>>>(xbuf, Wf + 1 * DIM * DIM, shf + 1 * DIM,
                                                           batch, lw + 1, Z, segmx);
    add_out_kernel<<<8, 256, 0, stream>>>(segmx, out);

    // ---- layer 2 ----
    hipMemsetAsync(agg, 0, (size_t)N_NODES * DIM * sizeof(float), stream);
    segsum_kernel<<<seg_blocks, 256, 0, stream>>>(xbuf, src, dst, agg);
    conv_mlp_kernel<<<mlp_blocks, 256, 0, stream>>>(xbuf, agg, Wf + 4 * DIM * DIM, shf + 4 * DIM, xout);
    hipMemsetAsync(segmx, 0, N_GROUPS * DIM * sizeof(unsigned), stream);
    lin_mlp_kernel<false><<<linm_blocks, 256, 0, stream>>>(xout, Wf + 2 * DIM * DIM, shf + 2 * DIM,
                                                           batch, lw + 2, Z, segmx);
    add_out_kernel<<<8, 256, 0, stream>>>(segmx, out);
}